// Round 1
// 427.638 us; speedup vs baseline: 1.1063x; 1.1063x over previous
//
#include <hip/hip_runtime.h>
#include <hip/hip_bf16.h>
#include <cstdint>

// MoE feed-forward, routed top-2 of 8 experts.
// B=2 S=2048 D=1024 F=2048 E=8 K=2.
// R6: (a) fuse gemm1a+gemm1b into one dual-accumulator kernel (shared A tile,
//     32 MFMA per K-step per wave vs 16, silu applied to fp32 acc directly,
//     h1raw round-trip deleted). R5 counters: MfmaUtil 16% -> barrier/staging
//     overhead dominates; doubling MFMA per barrier attacks that directly.
//     (b) XOR chunk swizzle on LDS staging/reads: [128][32] bf16 rows are 64B,
//     quarter-wave ds_read_b128 hit 2 bank-quads -> ~8-way conflict
//     (SQ_LDS_BANK_CONFLICT 4.39M/dispatch). global_load_lds writes linearly,
//     so swizzle the per-lane GLOBAL source chunk (chunk ^= (row>>1)&3) and
//     read with the matching XOR (rule: both-sides-or-neither).
//     (c) route_kernel widened 256->1024 threads (8 items/thread).

#define Dd 1024
#define Ff 2048
#define Ee 8
#define TOK 4096
#define PAIRS 8192

typedef __attribute__((ext_vector_type(8))) short short8;
typedef __attribute__((ext_vector_type(4))) float floatx4;

__device__ __forceinline__ unsigned short f2bf(float f) {
    unsigned int u = __float_as_uint(f);
    unsigned int r = (u + 0x7FFFu + ((u >> 16) & 1u)) >> 16;
    return (unsigned short)r;
}
__device__ __forceinline__ float bf2f(unsigned short u) {
    return __uint_as_float(((unsigned)u) << 16);
}

// async 16B/lane global->LDS. lds ptr is wave-uniform; lane i lands at lds + i*16B.
__device__ __forceinline__ void gload16(const unsigned short* g, unsigned short* l) {
    __builtin_amdgcn_global_load_lds(
        (const __attribute__((address_space(1))) unsigned int*)g,
        (__attribute__((address_space(3))) unsigned int*)l,
        16, 0, 0);
}

// ---------------- zero out (fallback path only) ----------------
__global__ void zero_kernel(float* __restrict__ out, int n4) {
    int i = blockIdx.x * blockDim.x + threadIdx.x;
    if (i < n4) reinterpret_cast<float4*>(out)[i] = make_float4(0.f, 0.f, 0.f, 0.f);
}

// ---------------- gating: fp32 scores, top-2, softmax (NO atomics) ----------------
__global__ void gating_kernel(const float* __restrict__ x, const float* __restrict__ Wg,
                              int* __restrict__ tok_idx, float* __restrict__ tok_prob) {
    int lane = threadIdx.x & 63;
    int w = threadIdx.x >> 6;
    int t = blockIdx.x * 4 + w;

    float xr[16];
    const float* xp = x + (size_t)t * Dd;
#pragma unroll
    for (int i = 0; i < 16; i++) xr[i] = xp[lane + i * 64];

    float sc[Ee];
    for (int e = 0; e < Ee; e++) {
        const float* wp = Wg + (size_t)e * Dd;
        float p = 0.f;
#pragma unroll
        for (int i = 0; i < 16; i++) p += xr[i] * wp[lane + i * 64];
        for (int off = 32; off > 0; off >>= 1) p += __shfl_xor(p, off);
        sc[e] = p;
    }
    if (lane == 0) {
        int e1 = 0, e2 = 0;
        float b1 = -1e30f, b2 = -1e30f;
        for (int e = 0; e < Ee; e++) {
            float s = sc[e];
            if (s > b1) { b2 = b1; e2 = e1; b1 = s; e1 = e; }
            else if (s > b2) { b2 = s; e2 = e; }
        }
        float p1 = 1.f / (1.f + expf(b2 - b1));
        float p2 = 1.f - p1;
        tok_idx[t * 2 + 0] = e1;
        tok_idx[t * 2 + 1] = e2;
        tok_prob[t * 2 + 0] = p1;
        tok_prob[t * 2 + 1] = p2;
    }
}

// ---------------- route: fused count + scan + stable scatter, one block ----------------
// 1024 threads x 8 items = 8192 (t,k) assignments. No global atomics, deterministic.
__global__ __launch_bounds__(1024) void route_kernel(
    const int* __restrict__ tok_idx, const float* __restrict__ tok_prob,
    int* __restrict__ meta, int* __restrict__ list_tok,
    float* __restrict__ list_prob, int* __restrict__ pos_of) {
    int tid = threadIdx.x;
    int lane = tid & 63, w = tid >> 6;   // 16 waves

    int e_loc[8];
#pragma unroll
    for (int j = 0; j < 8; j++) e_loc[j] = tok_idx[tid * 8 + j];

    // private histogram (static indexing only)
    int h[Ee];
#pragma unroll
    for (int e = 0; e < Ee; e++) {
        int c = 0;
#pragma unroll
        for (int j = 0; j < 8; j++) c += (e_loc[j] == e) ? 1 : 0;
        h[e] = c;
    }

    // per-expert exclusive prefix across the wave's 64 lanes + wave totals
    int pre[Ee], tot[Ee];
#pragma unroll
    for (int e = 0; e < Ee; e++) {
        int v = h[e];
        for (int d = 1; d < 64; d <<= 1) {
            int u = __shfl_up(v, d, 64);
            if (lane >= d) v += u;
        }
        pre[e] = v - h[e];
        tot[e] = __shfl(v, 63, 64);
    }

    __shared__ int wtot[16][Ee];
    __shared__ int wbase[16][Ee];
    __shared__ int ebase[Ee];
    if (lane == 0)
#pragma unroll
        for (int e = 0; e < Ee; e++) wtot[w][e] = tot[e];
    __syncthreads();
    if (tid == 0) {
        int etot[Ee];
        for (int e = 0; e < Ee; e++) {
            int s = 0;
            for (int ww = 0; ww < 16; ww++) { wbase[ww][e] = s; s += wtot[ww][e]; }
            etot[e] = s;
        }
        int b = 0;
        for (int e = 0; e < Ee; e++) {
            ebase[e] = b;
            meta[e] = etot[e];       // counts
            meta[16 + e] = b;        // bases
            b += etot[e];
        }
    }
    __syncthreads();

    int off[Ee];
#pragma unroll
    for (int e = 0; e < Ee; e++) off[e] = ebase[e] + wbase[w][e] + pre[e];

#pragma unroll
    for (int j = 0; j < 8; j++) {
        int item = tid * 8 + j;
        int el = e_loc[j];
        int pos = 0;
#pragma unroll
        for (int e = 0; e < Ee; e++) {
            if (el == e) { pos = off[e]; off[e] = pos + 1; }
        }
        list_tok[pos] = item >> 1;
        list_prob[pos] = tok_prob[item];
        pos_of[item] = pos;
    }
}

// ---------------- fp32 -> bf16 convert ----------------
__global__ void cvt_kernel(const float* __restrict__ src, unsigned short* __restrict__ dst, int n4) {
    int i = blockIdx.x * blockDim.x + threadIdx.x;
    if (i >= n4) return;
    float4 v = reinterpret_cast<const float4*>(src)[i];
    uint2 o;
    o.x = (unsigned)f2bf(v.x) | ((unsigned)f2bf(v.y) << 16);
    o.y = (unsigned)f2bf(v.z) | ((unsigned)f2bf(v.w) << 16);
    reinterpret_cast<uint2*>(dst)[i] = o;
}

// ---------------- manual fp32->bf16 LDS staging (fallback path only, linear) ----------------
__device__ __forceinline__ void stage16(unsigned short* dst, const float* src) {
    const float4* s = reinterpret_cast<const float4*>(src);
    float4 v0 = s[0], v1 = s[1], v2 = s[2], v3 = s[3];
    uint4 o0, o1;
    o0.x = (unsigned)f2bf(v0.x) | ((unsigned)f2bf(v0.y) << 16);
    o0.y = (unsigned)f2bf(v0.z) | ((unsigned)f2bf(v0.w) << 16);
    o0.z = (unsigned)f2bf(v1.x) | ((unsigned)f2bf(v1.y) << 16);
    o0.w = (unsigned)f2bf(v1.z) | ((unsigned)f2bf(v1.w) << 16);
    o1.x = (unsigned)f2bf(v2.x) | ((unsigned)f2bf(v2.y) << 16);
    o1.y = (unsigned)f2bf(v2.z) | ((unsigned)f2bf(v2.w) << 16);
    o1.z = (unsigned)f2bf(v3.x) | ((unsigned)f2bf(v3.y) << 16);
    o1.w = (unsigned)f2bf(v3.z) | ((unsigned)f2bf(v3.w) << 16);
    uint4* d = reinterpret_cast<uint4*>(dst);
    d[0] = o0;
    d[1] = o1;
}

// ============ fused gemm1: hidden = silu(x W1^T) * (x W2^T), routed rows ============
// 128x128 tile, BK=32, dual accumulator (acc1 for W1, acc2 for W2).
// 32 MFMA per K-step per wave between one barrier pair (2x the m97 density).
// LDS chunk swizzle: LDS[row][c] holds global chunk c ^ ((row>>1)&3); reads XOR back.
__global__ __launch_bounds__(256, 2) void rgemm12_kernel(
    const unsigned short* __restrict__ A,      // xb
    const unsigned short* __restrict__ B1w,    // W1b
    const unsigned short* __restrict__ B2w,    // W2b
    unsigned short* __restrict__ hout,         // hidden (bf16)
    const int* __restrict__ list_tok, const int* __restrict__ meta) {
    int e = blockIdx.z;
    int cnt = meta[e];
    int m0 = blockIdx.y * 128;
    if (m0 >= cnt) return;
    int bs = meta[16 + e];
    int n0 = blockIdx.x * 128;

    __shared__ unsigned short sA[128 * 32];
    __shared__ unsigned short sB1[128 * 32];
    __shared__ unsigned short sB2[128 * 32];

    int tid = threadIdx.x;
    int lane = tid & 63, w = tid >> 6;
    int wm = w >> 1, wn = w & 1;
    int lane15 = lane & 15, quad = lane >> 4;

    // staging geometry: wave w stages rows [w*32, w*32+16) then +16.
    // swizzled source chunk: lane's row jr has (jr>>1)&3 == (lane>>3)&3.
    int jr = w * 32 + (lane >> 2);
    int c8 = (((lane & 3) ^ ((lane >> 3) & 3)) * 8);
    unsigned short* ldsA0  = sA  + w * 1024;
    unsigned short* ldsA1  = ldsA0 + 512;
    unsigned short* ldsB10 = sB1 + w * 1024;
    unsigned short* ldsB11 = ldsB10 + 512;
    unsigned short* ldsB20 = sB2 + w * 1024;
    unsigned short* ldsB21 = ldsB20 + 512;

    int r0 = m0 + jr;      if (r0 >= cnt) r0 = cnt - 1;
    int r1 = m0 + jr + 16; if (r1 >= cnt) r1 = cnt - 1;
    size_t ar0 = (size_t)list_tok[bs + r0];
    size_t ar1 = (size_t)list_tok[bs + r1];
    const unsigned short* a0 = A + ar0 * Dd + c8;
    const unsigned short* a1 = A + ar1 * Dd + c8;
    const unsigned short* b10 = B1w + ((size_t)e * Ff + n0 + jr) * Dd + c8;
    const unsigned short* b11 = b10 + (size_t)16 * Dd;
    const unsigned short* b20 = B2w + ((size_t)e * Ff + n0 + jr) * Dd + c8;
    const unsigned short* b21 = b20 + (size_t)16 * Dd;

    // read-side swizzle: for fragment row (.. + lane15), (row>>1)&3 == (lane15>>1)&3
    // independent of mi/wm -> folds into the base pointer.
    int rsw = (lane15 >> 1) & 3;
    const unsigned short* sAr  = &sA [(wm * 64 + lane15) * 32 + (quad ^ rsw) * 8];
    const unsigned short* sB1r = &sB1[(wn * 64 + lane15) * 32 + (quad ^ rsw) * 8];
    const unsigned short* sB2r = &sB2[(wn * 64 + lane15) * 32 + (quad ^ rsw) * 8];

    floatx4 acc1[4][4] = {};
    floatx4 acc2[4][4] = {};

    for (int k0 = 0; k0 < Dd; k0 += 32) {
        gload16(a0 + k0, ldsA0);
        gload16(a1 + k0, ldsA1);
        gload16(b10 + k0, ldsB10);
        gload16(b11 + k0, ldsB11);
        gload16(b20 + k0, ldsB20);
        gload16(b21 + k0, ldsB21);
        __syncthreads();
        short8 af[4], b1f[4], b2f[4];
#pragma unroll
        for (int i = 0; i < 4; i++) {
            af[i]  = *reinterpret_cast<const short8*>(sAr  + i * 16 * 32);
            b1f[i] = *reinterpret_cast<const short8*>(sB1r + i * 16 * 32);
            b2f[i] = *reinterpret_cast<const short8*>(sB2r + i * 16 * 32);
        }
#pragma unroll
        for (int mi = 0; mi < 4; mi++)
#pragma unroll
            for (int ni = 0; ni < 4; ni++) {
                acc1[mi][ni] = __builtin_amdgcn_mfma_f32_16x16x32_bf16(af[mi], b1f[ni], acc1[mi][ni], 0, 0, 0);
                acc2[mi][ni] = __builtin_amdgcn_mfma_f32_16x16x32_bf16(af[mi], b2f[ni], acc2[mi][ni], 0, 0, 0);
            }
        __syncthreads();
    }

    // epilogue: hidden = silu(h1) * h2, silu on full-precision acc
#pragma unroll
    for (int mi = 0; mi < 4; mi++) {
#pragma unroll
        for (int i = 0; i < 4; i++) {
            int rr = m0 + wm * 64 + mi * 16 + quad * 4 + i;
            if (rr < cnt) {
                int pos = bs + rr;
                unsigned short* hp = hout + (size_t)pos * Ff + n0 + wn * 64;
#pragma unroll
                for (int ni = 0; ni < 4; ni++) {
                    float h1 = acc1[mi][ni][i];
                    float h2 = acc2[mi][ni][i];
                    float hv = h1 / (1.f + expf(-h1)) * h2;
                    hp[ni * 16 + lane15] = f2bf(hv);
                }
            }
        }
    }
}

// ============ routed single-acc GEMM kernels (m97 shape) ============
// EPI: 0 = store bf16 C to h1raw
//      1 = read h1raw, hidden = silu(h1)*C (bf16)
//      2 = store fp32 C to y[pos]
// BF path carries the LDS chunk swizzle; float fallback stays linear (stage16).
template <typename WT, int EPI>
__global__ __launch_bounds__(256) void rgemm_kernel(
    const unsigned short* __restrict__ A,      // row source (xb or hidden), stride AK
    const WT* __restrict__ Bw,                 // weights, rows of length AK
    unsigned short* __restrict__ h1raw,        // EPI 0 write / EPI 1 read
    unsigned short* __restrict__ hout,         // EPI 1 write
    float* __restrict__ y,                     // EPI 2 write
    const int* __restrict__ list_tok, const int* __restrict__ meta,
    int AK, int BN, int arow_is_list) {
    constexpr bool BF = (sizeof(WT) == 2);
    int e = blockIdx.z;
    int cnt = meta[e];
    int m0 = blockIdx.y * 128;
    if (m0 >= cnt) return;
    int bs = meta[16 + e];
    int n0 = blockIdx.x * 128;

    __shared__ unsigned short sA[128 * 32];
    __shared__ unsigned short sB[128 * 32];

    int tid = threadIdx.x;
    int lane = tid & 63, w = tid >> 6;
    int wm = w >> 1, wn = w & 1;
    int lane15 = lane & 15, quad = lane >> 4;

    // async staging geometry: wave w stages rows [w*32, w*32+16) then +16
    int jr = w * 32 + (lane >> 2);
    int c8 = BF ? ((((lane & 3) ^ ((lane >> 3) & 3))) * 8) : ((lane & 3) * 8);
    unsigned short* ldsA0 = sA + w * 1024;
    unsigned short* ldsA1 = ldsA0 + 512;
    unsigned short* ldsB0 = sB + w * 1024;
    unsigned short* ldsB1 = ldsB0 + 512;

    int r0 = m0 + jr;      if (r0 >= cnt) r0 = cnt - 1;
    int r1 = m0 + jr + 16; if (r1 >= cnt) r1 = cnt - 1;
    size_t ar0 = arow_is_list ? (size_t)list_tok[bs + r0] : (size_t)(bs + r0);
    size_t ar1 = arow_is_list ? (size_t)list_tok[bs + r1] : (size_t)(bs + r1);
    const unsigned short* a0 = A + ar0 * AK + c8;
    const unsigned short* a1 = A + ar1 * AK + c8;

    const WT *b0 = nullptr, *b1 = nullptr, *bmp = nullptr;
    unsigned short* sBw = nullptr;
    if constexpr (BF) {
        b0 = Bw + ((size_t)e * BN + n0 + jr) * AK + c8;
        b1 = Bw + ((size_t)e * BN + n0 + jr + 16) * AK + c8;
    } else {
        int row = tid >> 1, colb = (tid & 1) * 16;
        bmp = Bw + ((size_t)e * BN + n0 + row) * AK + colb;
        sBw = &sB[row * 32 + colb];
    }

    int rsw = BF ? ((lane15 >> 1) & 3) : 0;
    const unsigned short* sAr = &sA[(wm * 64 + lane15) * 32 + (quad ^ rsw) * 8];
    const unsigned short* sBr = &sB[(wn * 64 + lane15) * 32 + (quad ^ rsw) * 8];

    floatx4 acc[4][4] = {};

    for (int k0 = 0; k0 < AK; k0 += 32) {
        gload16(a0 + k0, ldsA0);
        gload16(a1 + k0, ldsA1);
        if constexpr (BF) {
            gload16(b0 + k0, ldsB0);
            gload16(b1 + k0, ldsB1);
        } else {
            stage16(sBw, bmp + k0);
        }
        __syncthreads();
        short8 af[4], bfr[4];
#pragma unroll
        for (int i = 0; i < 4; i++) {
            af[i]  = *reinterpret_cast<const short8*>(sAr + i * 16 * 32);
            bfr[i] = *reinterpret_cast<const short8*>(sBr + i * 16 * 32);
        }
#pragma unroll
        for (int mi = 0; mi < 4; mi++)
#pragma unroll
            for (int ni = 0; ni < 4; ni++)
                acc[mi][ni] = __builtin_amdgcn_mfma_f32_16x16x32_bf16(af[mi], bfr[ni], acc[mi][ni], 0, 0, 0);
        __syncthreads();
    }

#pragma unroll
    for (int mi = 0; mi < 4; mi++) {
#pragma unroll
        for (int i = 0; i < 4; i++) {
            int rr = m0 + wm * 64 + mi * 16 + quad * 4 + i;
            if (rr < cnt) {
                int pos = bs + rr;
                if constexpr (EPI == 0) {
                    unsigned short* hp = h1raw + (size_t)pos * BN + n0 + wn * 64;
#pragma unroll
                    for (int ni = 0; ni < 4; ni++)
                        hp[ni * 16 + lane15] = f2bf(acc[mi][ni][i]);
                } else if constexpr (EPI == 1) {
                    const unsigned short* h1p = h1raw + (size_t)pos * BN + n0 + wn * 64;
                    unsigned short* hp = hout + (size_t)pos * BN + n0 + wn * 64;
#pragma unroll
                    for (int ni = 0; ni < 4; ni++) {
                        float h1 = bf2f(h1p[ni * 16 + lane15]);
                        float h2 = acc[mi][ni][i];
                        float hv = h1 / (1.f + expf(-h1)) * h2;
                        hp[ni * 16 + lane15] = f2bf(hv);
                    }
                } else {
                    float* yp = y + (size_t)pos * BN + n0 + wn * 64;
#pragma unroll
                    for (int ni = 0; ni < 4; ni++)
                        yp[ni * 16 + lane15] = acc[mi][ni][i];
                }
            }
        }
    }
}

// ---------------- combine: out[t] = p0*y[pos0] + p1*y[pos1] ----------------
__global__ void combine_kernel(const float* __restrict__ y,
                               const int* __restrict__ pos_of,
                               const float* __restrict__ tok_prob,
                               float* __restrict__ out) {
    int i = blockIdx.x * 256 + threadIdx.x;   // over TOK * Dd/4
    int t = i >> 8;                           // Dd/4 == 256
    int c = i & 255;
    int p0 = pos_of[t * 2], p1 = pos_of[t * 2 + 1];
    float w0 = tok_prob[t * 2], w1 = tok_prob[t * 2 + 1];
    float4 a = reinterpret_cast<const float4*>(y + (size_t)p0 * Dd)[c];
    float4 b = reinterpret_cast<const float4*>(y + (size_t)p1 * Dd)[c];
    float4 o;
    o.x = w0 * a.x + w1 * b.x;
    o.y = w0 * a.y + w1 * b.y;
    o.z = w0 * a.z + w1 * b.z;
    o.w = w0 * a.w + w1 * b.w;
    reinterpret_cast<float4*>(out + (size_t)t * Dd)[c] = o;
}

// ---------------- host launch ----------------
extern "C" void kernel_launch(void* const* d_in, const int* in_sizes, int n_in,
                              void* d_out, int out_size, void* d_ws, size_t ws_size,
                              hipStream_t stream) {
    const float* x  = (const float*)d_in[0];
    const float* Wg = (const float*)d_in[1];
    const float* W1 = (const float*)d_in[2];
    const float* W2 = (const float*)d_in[3];
    const float* W3 = (const float*)d_in[4];
    float* out = (float*)d_out;

    char* ws = (char*)d_ws;
    size_t off = 0;
    auto alloc = [&](size_t bytes) -> char* {
        size_t o = off;
        off += (bytes + 255) & ~(size_t)255;
        return ws + o;
    };

    int* meta = (int*)alloc(64 * sizeof(int));
    int* tok_idx = (int*)alloc((size_t)TOK * 2 * sizeof(int));
    float* tok_prob = (float*)alloc((size_t)TOK * 2 * sizeof(float));
    int* pos_of = (int*)alloc((size_t)TOK * 2 * sizeof(int));
    int* list_tok = (int*)alloc((size_t)PAIRS * sizeof(int));
    float* list_prob = (float*)alloc((size_t)PAIRS * sizeof(float));
    unsigned short* xb = (unsigned short*)alloc((size_t)TOK * Dd * sizeof(unsigned short));
    unsigned short* hidden = (unsigned short*)alloc((size_t)PAIRS * Ff * sizeof(unsigned short));
    unsigned short* h1raw = (unsigned short*)alloc((size_t)PAIRS * Ff * sizeof(unsigned short));  // fallback path only

    // bf16 weight copies; y (32 MB fp32) OVERLAYS W1b (32 MB bf16):
    // W1b read only in rgemm12; y written only in gemm2/combine (stream-ordered later).
    size_t wbytes = (size_t)Ee * Ff * Dd * sizeof(unsigned short);
    size_t ybytes = (size_t)PAIRS * Dd * sizeof(float);
    bool has_w = (ws_size >= off + 3 * wbytes + 4096);
    unsigned short *W1b = nullptr, *W2b = nullptr, *W3b = nullptr;
    float* y = nullptr;
    bool has_y = false;
    if (has_w) {
        W1b = (unsigned short*)alloc(wbytes);
        W2b = (unsigned short*)alloc(wbytes);
        W3b = (unsigned short*)alloc(wbytes);
        y = (float*)W1b;           // overlay
        has_y = true;
    } else if (ws_size >= off + ybytes + 4096) {
        y = (float*)alloc(ybytes);
        has_y = true;
    }

    gating_kernel<<<dim3(TOK / 4), dim3(256), 0, stream>>>(x, Wg, tok_idx, tok_prob);
    route_kernel<<<dim3(1), dim3(1024), 0, stream>>>(tok_idx, tok_prob, meta,
                                                     list_tok, list_prob, pos_of);

    int xn4 = TOK * Dd / 4;
    cvt_kernel<<<dim3((xn4 + 255) / 256), dim3(256), 0, stream>>>(x, xb, xn4);

    dim3 g1(Ff / 128, 32, Ee), g2(Dd / 128, 32, Ee), blk(256);

    if (has_w) {
        int wn4 = Ee * Ff * Dd / 4;
        cvt_kernel<<<dim3((wn4 + 255) / 256), blk, 0, stream>>>(W1, W1b, wn4);
        cvt_kernel<<<dim3((wn4 + 255) / 256), blk, 0, stream>>>(W2, W2b, wn4);
        cvt_kernel<<<dim3((wn4 + 255) / 256), blk, 0, stream>>>(W3, W3b, wn4);
        // fused gemm1: hidden = silu(x W1^T) * (x W2^T)
        rgemm12_kernel<<<g1, blk, 0, stream>>>(xb, W1b, W2b, hidden, list_tok, meta);
        // gemm2: y = hidden W3^T
        rgemm_kernel<unsigned short, 2><<<g2, blk, 0, stream>>>(
            hidden, W3b, nullptr, nullptr, y, list_tok, meta, Ff, Dd, 0);
        combine_kernel<<<dim3(TOK * Dd / 4 / 256), blk, 0, stream>>>(y, pos_of, tok_prob, out);
    } else if (has_y) {
        rgemm_kernel<float, 0><<<g1, blk, 0, stream>>>(
            xb, W1, h1raw, nullptr, nullptr, list_tok, meta, Dd, Ff, 1);
        rgemm_kernel<float, 1><<<g1, blk, 0, stream>>>(
            xb, W2, h1raw, hidden, nullptr, list_tok, meta, Dd, Ff, 1);
        rgemm_kernel<float, 2><<<g2, blk, 0, stream>>>(
            hidden, W3, nullptr, nullptr, y, list_tok, meta, Ff, Dd, 0);
        combine_kernel<<<dim3(TOK * Dd / 4 / 256), blk, 0, stream>>>(y, pos_of, tok_prob, out);
    }
}

// Round 2
// 427.223 us; speedup vs baseline: 1.1074x; 1.0010x over previous
//
#include <hip/hip_runtime.h>
#include <hip/hip_bf16.h>
#include <cstdint>

// MoE feed-forward, routed top-2 of 8 experts.
// B=2 S=2048 D=1024 F=2048 E=8 K=2.
// R7: (a) 2-phase double-buffered K-loop in both GEMMs (T3-minimum): issue
//     next-tile global_load_lds BEFORE this tile's ds_read+MFMA, ONE
//     __syncthreads per K-step (its vmcnt(0) drain now sits after ~300cy of
//     MFMA instead of before any compute). R6 counters: MfmaUtil 25%,
//     Occupancy 16% (~2 blocks/CU) -> intra-block overlap is the only
//     latency hider available.
//     (b) combine fused into gemm2 epilogue via atomicAdd(out + tok*D, p*acc):
//     deletes y (32MB write + 32MB read) and the combine dispatch; out is
//     zero-filled first. Exactly 2 contributions per element, distinct
//     addresses -> no contention; fp32 order noise ~1e-6 << tolerance.
//     (kept from R6: dual-acc fused gemm1, XOR chunk swizzle -> 0 conflicts)

#define Dd 1024
#define Ff 2048
#define Ee 8
#define TOK 4096
#define PAIRS 8192

typedef __attribute__((ext_vector_type(8))) short short8;
typedef __attribute__((ext_vector_type(4))) float floatx4;

__device__ __forceinline__ unsigned short f2bf(float f) {
    unsigned int u = __float_as_uint(f);
    unsigned int r = (u + 0x7FFFu + ((u >> 16) & 1u)) >> 16;
    return (unsigned short)r;
}
__device__ __forceinline__ float bf2f(unsigned short u) {
    return __uint_as_float(((unsigned)u) << 16);
}

// async 16B/lane global->LDS. lds ptr is wave-uniform; lane i lands at lds + i*16B.
__device__ __forceinline__ void gload16(const unsigned short* g, unsigned short* l) {
    __builtin_amdgcn_global_load_lds(
        (const __attribute__((address_space(1))) unsigned int*)g,
        (__attribute__((address_space(3))) unsigned int*)l,
        16, 0, 0);
}

// ---------------- zero out ----------------
__global__ void zero_kernel(float* __restrict__ out, int n4) {
    int i = blockIdx.x * blockDim.x + threadIdx.x;
    if (i < n4) reinterpret_cast<float4*>(out)[i] = make_float4(0.f, 0.f, 0.f, 0.f);
}

// ---------------- gating: fp32 scores, top-2, softmax (NO atomics) ----------------
__global__ void gating_kernel(const float* __restrict__ x, const float* __restrict__ Wg,
                              int* __restrict__ tok_idx, float* __restrict__ tok_prob) {
    int lane = threadIdx.x & 63;
    int w = threadIdx.x >> 6;
    int t = blockIdx.x * 4 + w;

    float xr[16];
    const float* xp = x + (size_t)t * Dd;
#pragma unroll
    for (int i = 0; i < 16; i++) xr[i] = xp[lane + i * 64];

    float sc[Ee];
    for (int e = 0; e < Ee; e++) {
        const float* wp = Wg + (size_t)e * Dd;
        float p = 0.f;
#pragma unroll
        for (int i = 0; i < 16; i++) p += xr[i] * wp[lane + i * 64];
        for (int off = 32; off > 0; off >>= 1) p += __shfl_xor(p, off);
        sc[e] = p;
    }
    if (lane == 0) {
        int e1 = 0, e2 = 0;
        float b1 = -1e30f, b2 = -1e30f;
        for (int e = 0; e < Ee; e++) {
            float s = sc[e];
            if (s > b1) { b2 = b1; e2 = e1; b1 = s; e1 = e; }
            else if (s > b2) { b2 = s; e2 = e; }
        }
        float p1 = 1.f / (1.f + expf(b2 - b1));
        float p2 = 1.f - p1;
        tok_idx[t * 2 + 0] = e1;
        tok_idx[t * 2 + 1] = e2;
        tok_prob[t * 2 + 0] = p1;
        tok_prob[t * 2 + 1] = p2;
    }
}

// ---------------- route: fused count + scan + stable scatter, one block ----------------
// 1024 threads x 8 items = 8192 (t,k) assignments. No global atomics, deterministic.
__global__ __launch_bounds__(1024) void route_kernel(
    const int* __restrict__ tok_idx, const float* __restrict__ tok_prob,
    int* __restrict__ meta, int* __restrict__ list_tok,
    float* __restrict__ list_prob, int* __restrict__ pos_of) {
    int tid = threadIdx.x;
    int lane = tid & 63, w = tid >> 6;   // 16 waves

    int e_loc[8];
#pragma unroll
    for (int j = 0; j < 8; j++) e_loc[j] = tok_idx[tid * 8 + j];

    // private histogram (static indexing only)
    int h[Ee];
#pragma unroll
    for (int e = 0; e < Ee; e++) {
        int c = 0;
#pragma unroll
        for (int j = 0; j < 8; j++) c += (e_loc[j] == e) ? 1 : 0;
        h[e] = c;
    }

    // per-expert exclusive prefix across the wave's 64 lanes + wave totals
    int pre[Ee], tot[Ee];
#pragma unroll
    for (int e = 0; e < Ee; e++) {
        int v = h[e];
        for (int d = 1; d < 64; d <<= 1) {
            int u = __shfl_up(v, d, 64);
            if (lane >= d) v += u;
        }
        pre[e] = v - h[e];
        tot[e] = __shfl(v, 63, 64);
    }

    __shared__ int wtot[16][Ee];
    __shared__ int wbase[16][Ee];
    __shared__ int ebase[Ee];
    if (lane == 0)
#pragma unroll
        for (int e = 0; e < Ee; e++) wtot[w][e] = tot[e];
    __syncthreads();
    if (tid == 0) {
        int etot[Ee];
        for (int e = 0; e < Ee; e++) {
            int s = 0;
            for (int ww = 0; ww < 16; ww++) { wbase[ww][e] = s; s += wtot[ww][e]; }
            etot[e] = s;
        }
        int b = 0;
        for (int e = 0; e < Ee; e++) {
            ebase[e] = b;
            meta[e] = etot[e];       // counts
            meta[16 + e] = b;        // bases
            b += etot[e];
        }
    }
    __syncthreads();

    int off[Ee];
#pragma unroll
    for (int e = 0; e < Ee; e++) off[e] = ebase[e] + wbase[w][e] + pre[e];

#pragma unroll
    for (int j = 0; j < 8; j++) {
        int item = tid * 8 + j;
        int el = e_loc[j];
        int pos = 0;
#pragma unroll
        for (int e = 0; e < Ee; e++) {
            if (el == e) { pos = off[e]; off[e] = pos + 1; }
        }
        list_tok[pos] = item >> 1;
        list_prob[pos] = tok_prob[item];
        pos_of[item] = pos;
    }
}

// ---------------- fp32 -> bf16 convert ----------------
__global__ void cvt_kernel(const float* __restrict__ src, unsigned short* __restrict__ dst, int n4) {
    int i = blockIdx.x * blockDim.x + threadIdx.x;
    if (i >= n4) return;
    float4 v = reinterpret_cast<const float4*>(src)[i];
    uint2 o;
    o.x = (unsigned)f2bf(v.x) | ((unsigned)f2bf(v.y) << 16);
    o.y = (unsigned)f2bf(v.z) | ((unsigned)f2bf(v.w) << 16);
    reinterpret_cast<uint2*>(dst)[i] = o;
}

// ---------------- manual fp32->bf16 LDS staging (fallback path only, linear) ----------------
__device__ __forceinline__ void stage16(unsigned short* dst, const float* src) {
    const float4* s = reinterpret_cast<const float4*>(src);
    float4 v0 = s[0], v1 = s[1], v2 = s[2], v3 = s[3];
    uint4 o0, o1;
    o0.x = (unsigned)f2bf(v0.x) | ((unsigned)f2bf(v0.y) << 16);
    o0.y = (unsigned)f2bf(v0.z) | ((unsigned)f2bf(v0.w) << 16);
    o0.z = (unsigned)f2bf(v1.x) | ((unsigned)f2bf(v1.y) << 16);
    o0.w = (unsigned)f2bf(v1.z) | ((unsigned)f2bf(v1.w) << 16);
    o1.x = (unsigned)f2bf(v2.x) | ((unsigned)f2bf(v2.y) << 16);
    o1.y = (unsigned)f2bf(v2.z) | ((unsigned)f2bf(v2.w) << 16);
    o1.z = (unsigned)f2bf(v3.x) | ((unsigned)f2bf(v3.y) << 16);
    o1.w = (unsigned)f2bf(v3.z) | ((unsigned)f2bf(v3.w) << 16);
    uint4* d = reinterpret_cast<uint4*>(dst);
    d[0] = o0;
    d[1] = o1;
}

// ============ fused gemm1: hidden = silu(x W1^T) * (x W2^T), routed rows ============
// 128x128 tile, BK=32, dual accumulator. 2-phase dbuf: stage(next) issued before
// ds_read+MFMA(cur); single __syncthreads per K-step (drain lands after compute).
// LDS chunk swizzle: LDS[row][c] holds global chunk c ^ ((row>>1)&3); reads XOR back.
__global__ __launch_bounds__(256, 2) void rgemm12_kernel(
    const unsigned short* __restrict__ A,      // xb
    const unsigned short* __restrict__ B1w,    // W1b
    const unsigned short* __restrict__ B2w,    // W2b
    unsigned short* __restrict__ hout,         // hidden (bf16)
    const int* __restrict__ list_tok, const int* __restrict__ meta) {
    int e = blockIdx.z;
    int cnt = meta[e];
    int m0 = blockIdx.y * 128;
    if (m0 >= cnt) return;
    int bs = meta[16 + e];
    int n0 = blockIdx.x * 128;

    __shared__ unsigned short sA[2 * 128 * 32];
    __shared__ unsigned short sB1[2 * 128 * 32];
    __shared__ unsigned short sB2[2 * 128 * 32];

    int tid = threadIdx.x;
    int lane = tid & 63, w = tid >> 6;
    int wm = w >> 1, wn = w & 1;
    int lane15 = lane & 15, quad = lane >> 4;

    // staging geometry: wave w stages rows [w*32, w*32+16) then +16.
    // swizzled source chunk: lane's row jr has (jr>>1)&3 == (lane>>3)&3.
    int jr = w * 32 + (lane >> 2);
    int c8 = (((lane & 3) ^ ((lane >> 3) & 3)) * 8);
    unsigned short* ldsA0  = sA  + w * 1024;
    unsigned short* ldsA1  = ldsA0 + 512;
    unsigned short* ldsB10 = sB1 + w * 1024;
    unsigned short* ldsB11 = ldsB10 + 512;
    unsigned short* ldsB20 = sB2 + w * 1024;
    unsigned short* ldsB21 = ldsB20 + 512;

    int r0 = m0 + jr;      if (r0 >= cnt) r0 = cnt - 1;
    int r1 = m0 + jr + 16; if (r1 >= cnt) r1 = cnt - 1;
    size_t ar0 = (size_t)list_tok[bs + r0];
    size_t ar1 = (size_t)list_tok[bs + r1];
    const unsigned short* a0 = A + ar0 * Dd + c8;
    const unsigned short* a1 = A + ar1 * Dd + c8;
    const unsigned short* b10 = B1w + ((size_t)e * Ff + n0 + jr) * Dd + c8;
    const unsigned short* b11 = b10 + (size_t)16 * Dd;
    const unsigned short* b20 = B2w + ((size_t)e * Ff + n0 + jr) * Dd + c8;
    const unsigned short* b21 = b20 + (size_t)16 * Dd;

    // read-side swizzle: fragment row is (..+lane15); (row>>1)&3 == (lane15>>1)&3,
    // independent of mi/wm -> folds into the base pointer.
    int rsw = (lane15 >> 1) & 3;
    const unsigned short* sAr  = &sA [(wm * 64 + lane15) * 32 + (quad ^ rsw) * 8];
    const unsigned short* sB1r = &sB1[(wn * 64 + lane15) * 32 + (quad ^ rsw) * 8];
    const unsigned short* sB2r = &sB2[(wn * 64 + lane15) * 32 + (quad ^ rsw) * 8];

    floatx4 acc1[4][4] = {};
    floatx4 acc2[4][4] = {};

    // prologue: stage K-step 0 into buffer 0
    gload16(a0, ldsA0);
    gload16(a1, ldsA1);
    gload16(b10, ldsB10);
    gload16(b11, ldsB11);
    gload16(b20, ldsB20);
    gload16(b21, ldsB21);
    __syncthreads();

    int cur = 0;
    for (int k0 = 0; k0 < Dd; k0 += 32) {
        if (k0 + 32 < Dd) {
            int o = (cur ^ 1) * 4096;
            int k = k0 + 32;
            gload16(a0 + k,  ldsA0  + o);
            gload16(a1 + k,  ldsA1  + o);
            gload16(b10 + k, ldsB10 + o);
            gload16(b11 + k, ldsB11 + o);
            gload16(b20 + k, ldsB20 + o);
            gload16(b21 + k, ldsB21 + o);
        }
        int o = cur * 4096;
        short8 af[4], b1f[4], b2f[4];
#pragma unroll
        for (int i = 0; i < 4; i++) {
            af[i]  = *reinterpret_cast<const short8*>(sAr  + o + i * 16 * 32);
            b1f[i] = *reinterpret_cast<const short8*>(sB1r + o + i * 16 * 32);
            b2f[i] = *reinterpret_cast<const short8*>(sB2r + o + i * 16 * 32);
        }
#pragma unroll
        for (int mi = 0; mi < 4; mi++)
#pragma unroll
            for (int ni = 0; ni < 4; ni++) {
                acc1[mi][ni] = __builtin_amdgcn_mfma_f32_16x16x32_bf16(af[mi], b1f[ni], acc1[mi][ni], 0, 0, 0);
                acc2[mi][ni] = __builtin_amdgcn_mfma_f32_16x16x32_bf16(af[mi], b2f[ni], acc2[mi][ni], 0, 0, 0);
            }
        __syncthreads();
        cur ^= 1;
    }

    // epilogue: hidden = silu(h1) * h2, silu on full-precision acc
#pragma unroll
    for (int mi = 0; mi < 4; mi++) {
#pragma unroll
        for (int i = 0; i < 4; i++) {
            int rr = m0 + wm * 64 + mi * 16 + quad * 4 + i;
            if (rr < cnt) {
                int pos = bs + rr;
                unsigned short* hp = hout + (size_t)pos * Ff + n0 + wn * 64;
#pragma unroll
                for (int ni = 0; ni < 4; ni++) {
                    float h1 = acc1[mi][ni][i];
                    float h2 = acc2[mi][ni][i];
                    float hv = h1 / (1.f + expf(-h1)) * h2;
                    hp[ni * 16 + lane15] = f2bf(hv);
                }
            }
        }
    }
}

// ============ routed single-acc GEMM (m97 shape, 2-phase dbuf) ============
// EPI: 0 = store bf16 C to h1raw
//      1 = read h1raw, hidden = silu(h1)*C (bf16)
//      2 = fused combine: atomicAdd(out[tok], prob * C)  (out pre-zeroed)
// BF path carries the LDS chunk swizzle; float fallback stays linear (stage16).
template <typename WT, int EPI>
__global__ __launch_bounds__(256) void rgemm_kernel(
    const unsigned short* __restrict__ A,      // row source (xb or hidden), stride AK
    const WT* __restrict__ Bw,                 // weights, rows of length AK
    unsigned short* __restrict__ h1raw,        // EPI 0 write / EPI 1 read
    unsigned short* __restrict__ hout,         // EPI 1 write
    float* __restrict__ out,                   // EPI 2: token-indexed atomic output
    const int* __restrict__ list_tok, const float* __restrict__ list_prob,
    const int* __restrict__ meta,
    int AK, int BN, int arow_is_list) {
    constexpr bool BF = (sizeof(WT) == 2);
    int e = blockIdx.z;
    int cnt = meta[e];
    int m0 = blockIdx.y * 128;
    if (m0 >= cnt) return;
    int bs = meta[16 + e];
    int n0 = blockIdx.x * 128;

    __shared__ unsigned short sA[2 * 128 * 32];
    __shared__ unsigned short sB[2 * 128 * 32];

    int tid = threadIdx.x;
    int lane = tid & 63, w = tid >> 6;
    int wm = w >> 1, wn = w & 1;
    int lane15 = lane & 15, quad = lane >> 4;

    // async staging geometry: wave w stages rows [w*32, w*32+16) then +16
    int jr = w * 32 + (lane >> 2);
    int c8 = BF ? ((((lane & 3) ^ ((lane >> 3) & 3))) * 8) : ((lane & 3) * 8);
    unsigned short* ldsA0 = sA + w * 1024;
    unsigned short* ldsA1 = ldsA0 + 512;
    unsigned short* ldsB0 = sB + w * 1024;
    unsigned short* ldsB1 = ldsB0 + 512;

    int r0 = m0 + jr;      if (r0 >= cnt) r0 = cnt - 1;
    int r1 = m0 + jr + 16; if (r1 >= cnt) r1 = cnt - 1;
    size_t ar0 = arow_is_list ? (size_t)list_tok[bs + r0] : (size_t)(bs + r0);
    size_t ar1 = arow_is_list ? (size_t)list_tok[bs + r1] : (size_t)(bs + r1);
    const unsigned short* a0 = A + ar0 * AK + c8;
    const unsigned short* a1 = A + ar1 * AK + c8;

    const WT *b0 = nullptr, *b1 = nullptr, *bmp = nullptr;
    unsigned short* sBw = nullptr;
    if constexpr (BF) {
        b0 = Bw + ((size_t)e * BN + n0 + jr) * AK + c8;
        b1 = Bw + ((size_t)e * BN + n0 + jr + 16) * AK + c8;
    } else {
        int row = tid >> 1, colb = (tid & 1) * 16;
        bmp = Bw + ((size_t)e * BN + n0 + row) * AK + colb;
        sBw = &sB[row * 32 + colb];
    }

    int rsw = BF ? ((lane15 >> 1) & 3) : 0;
    const unsigned short* sAr = &sA[(wm * 64 + lane15) * 32 + (quad ^ rsw) * 8];
    const unsigned short* sBr = &sB[(wn * 64 + lane15) * 32 + (quad ^ rsw) * 8];

    floatx4 acc[4][4] = {};

    // prologue: stage K-step 0 into buffer 0
    gload16(a0, ldsA0);
    gload16(a1, ldsA1);
    if constexpr (BF) {
        gload16(b0, ldsB0);
        gload16(b1, ldsB1);
    } else {
        stage16(sBw, bmp);
    }
    __syncthreads();

    int cur = 0;
    for (int k0 = 0; k0 < AK; k0 += 32) {
        if (k0 + 32 < AK) {
            int o = (cur ^ 1) * 4096;
            int k = k0 + 32;
            gload16(a0 + k, ldsA0 + o);
            gload16(a1 + k, ldsA1 + o);
            if constexpr (BF) {
                gload16(b0 + k, ldsB0 + o);
                gload16(b1 + k, ldsB1 + o);
            } else {
                stage16(sBw + o, bmp + k);
            }
        }
        int o = cur * 4096;
        short8 af[4], bfr[4];
#pragma unroll
        for (int i = 0; i < 4; i++) {
            af[i]  = *reinterpret_cast<const short8*>(sAr + o + i * 16 * 32);
            bfr[i] = *reinterpret_cast<const short8*>(sBr + o + i * 16 * 32);
        }
#pragma unroll
        for (int mi = 0; mi < 4; mi++)
#pragma unroll
            for (int ni = 0; ni < 4; ni++)
                acc[mi][ni] = __builtin_amdgcn_mfma_f32_16x16x32_bf16(af[mi], bfr[ni], acc[mi][ni], 0, 0, 0);
        __syncthreads();
        cur ^= 1;
    }

#pragma unroll
    for (int mi = 0; mi < 4; mi++) {
#pragma unroll
        for (int i = 0; i < 4; i++) {
            int rr = m0 + wm * 64 + mi * 16 + quad * 4 + i;
            if (rr < cnt) {
                int pos = bs + rr;
                if constexpr (EPI == 0) {
                    unsigned short* hp = h1raw + (size_t)pos * BN + n0 + wn * 64;
#pragma unroll
                    for (int ni = 0; ni < 4; ni++)
                        hp[ni * 16 + lane15] = f2bf(acc[mi][ni][i]);
                } else if constexpr (EPI == 1) {
                    const unsigned short* h1p = h1raw + (size_t)pos * BN + n0 + wn * 64;
                    unsigned short* hp = hout + (size_t)pos * BN + n0 + wn * 64;
#pragma unroll
                    for (int ni = 0; ni < 4; ni++) {
                        float h1 = bf2f(h1p[ni * 16 + lane15]);
                        float h2 = acc[mi][ni][i];
                        float hv = h1 / (1.f + expf(-h1)) * h2;
                        hp[ni * 16 + lane15] = f2bf(hv);
                    }
                } else {
                    int tok = list_tok[pos];
                    float p = list_prob[pos];
                    float* yp = out + (size_t)tok * BN + n0 + wn * 64;
#pragma unroll
                    for (int ni = 0; ni < 4; ni++)
                        atomicAdd(&yp[ni * 16 + lane15], p * acc[mi][ni][i]);
                }
            }
        }
    }
}

// ---------------- host launch ----------------
extern "C" void kernel_launch(void* const* d_in, const int* in_sizes, int n_in,
                              void* d_out, int out_size, void* d_ws, size_t ws_size,
                              hipStream_t stream) {
    const float* x  = (const float*)d_in[0];
    const float* Wg = (const float*)d_in[1];
    const float* W1 = (const float*)d_in[2];
    const float* W2 = (const float*)d_in[3];
    const float* W3 = (const float*)d_in[4];
    float* out = (float*)d_out;

    char* ws = (char*)d_ws;
    size_t off = 0;
    auto alloc = [&](size_t bytes) -> char* {
        size_t o = off;
        off += (bytes + 255) & ~(size_t)255;
        return ws + o;
    };

    int* meta = (int*)alloc(64 * sizeof(int));
    int* tok_idx = (int*)alloc((size_t)TOK * 2 * sizeof(int));
    float* tok_prob = (float*)alloc((size_t)TOK * 2 * sizeof(float));
    int* pos_of = (int*)alloc((size_t)TOK * 2 * sizeof(int));
    int* list_tok = (int*)alloc((size_t)PAIRS * sizeof(int));
    float* list_prob = (float*)alloc((size_t)PAIRS * sizeof(float));
    unsigned short* xb = (unsigned short*)alloc((size_t)TOK * Dd * sizeof(unsigned short));
    unsigned short* hidden = (unsigned short*)alloc((size_t)PAIRS * Ff * sizeof(unsigned short));
    unsigned short* h1raw = (unsigned short*)alloc((size_t)PAIRS * Ff * sizeof(unsigned short));  // fallback path only

    // bf16 weight copies
    size_t wbytes = (size_t)Ee * Ff * Dd * sizeof(unsigned short);
    bool has_w = (ws_size >= off + 3 * wbytes + 4096);
    unsigned short *W1b = nullptr, *W2b = nullptr, *W3b = nullptr;
    if (has_w) {
        W1b = (unsigned short*)alloc(wbytes);
        W2b = (unsigned short*)alloc(wbytes);
        W3b = (unsigned short*)alloc(wbytes);
    }

    // out pre-zeroed for the atomic-accumulate epilogue
    zero_kernel<<<dim3(TOK * Dd / 4 / 256), dim3(256), 0, stream>>>(out, TOK * Dd / 4);

    gating_kernel<<<dim3(TOK / 4), dim3(256), 0, stream>>>(x, Wg, tok_idx, tok_prob);
    route_kernel<<<dim3(1), dim3(1024), 0, stream>>>(tok_idx, tok_prob, meta,
                                                     list_tok, list_prob, pos_of);

    int xn4 = TOK * Dd / 4;
    cvt_kernel<<<dim3((xn4 + 255) / 256), dim3(256), 0, stream>>>(x, xb, xn4);

    dim3 g1(Ff / 128, 32, Ee), g2(Dd / 128, 32, Ee), blk(256);

    if (has_w) {
        int wn4 = Ee * Ff * Dd / 4;
        cvt_kernel<<<dim3((wn4 + 255) / 256), blk, 0, stream>>>(W1, W1b, wn4);
        cvt_kernel<<<dim3((wn4 + 255) / 256), blk, 0, stream>>>(W2, W2b, wn4);
        cvt_kernel<<<dim3((wn4 + 255) / 256), blk, 0, stream>>>(W3, W3b, wn4);
        // fused gemm1: hidden = silu(x W1^T) * (x W2^T)
        rgemm12_kernel<<<g1, blk, 0, stream>>>(xb, W1b, W2b, hidden, list_tok, meta);
        // gemm2 + combine: out[tok] += prob * (hidden W3^T)
        rgemm_kernel<unsigned short, 2><<<g2, blk, 0, stream>>>(
            hidden, W3b, nullptr, nullptr, out, list_tok, list_prob, meta, Ff, Dd, 0);
    } else {
        rgemm_kernel<float, 0><<<g1, blk, 0, stream>>>(
            xb, W1, h1raw, nullptr, nullptr, list_tok, list_prob, meta, Dd, Ff, 1);
        rgemm_kernel<float, 1><<<g1, blk, 0, stream>>>(
            xb, W2, h1raw, hidden, nullptr, list_tok, list_prob, meta, Dd, Ff, 1);
        rgemm_kernel<float, 2><<<g2, blk, 0, stream>>>(
            hidden, W3, nullptr, nullptr, out, list_tok, list_prob, meta, Ff, Dd, 0);
    }
}

// Round 3
// 425.455 us; speedup vs baseline: 1.1120x; 1.0042x over previous
//
#include <hip/hip_runtime.h>
#include <hip/hip_bf16.h>
#include <cstdint>

// MoE feed-forward, routed top-2 of 8 experts.
// B=2 S=2048 D=1024 F=2048 E=8 K=2.
// R8: counted-vmcnt software pipeline (T4) in both bf16 GEMMs.
//   R7 post-mortem: __syncthreads per K-step compiles to s_waitcnt vmcnt(0)
//   -> it DRAINED the prefetch issued just above it; dbuf was structurally
//   defeated (guide m99/m100). Fix: raw s_barrier + inline-asm
//   s_waitcnt vmcnt(6) (rgemm12) / vmcnt(4) (gemm2) -- never 0 in the main
//   loop; next tile's loads stay in flight across both barriers (m218:
//   counted-vs-drain0 = +38..73%). setprio(1) around MFMA cluster (T5,
//   role-split now exists). Memory-clobber asm fences pin ordering.
//   (kept: dual-acc fused gemm1, XOR chunk swizzle -> 0 conflicts,
//    atomic combine in gemm2 epilogue)

#define Dd 1024
#define Ff 2048
#define Ee 8
#define TOK 4096
#define PAIRS 8192

typedef __attribute__((ext_vector_type(8))) short short8;
typedef __attribute__((ext_vector_type(4))) float floatx4;

__device__ __forceinline__ unsigned short f2bf(float f) {
    unsigned int u = __float_as_uint(f);
    unsigned int r = (u + 0x7FFFu + ((u >> 16) & 1u)) >> 16;
    return (unsigned short)r;
}
__device__ __forceinline__ float bf2f(unsigned short u) {
    return __uint_as_float(((unsigned)u) << 16);
}

// async 16B/lane global->LDS. lds ptr is wave-uniform; lane i lands at lds + i*16B.
__device__ __forceinline__ void gload16(const unsigned short* g, unsigned short* l) {
    __builtin_amdgcn_global_load_lds(
        (const __attribute__((address_space(1))) unsigned int*)g,
        (__attribute__((address_space(3))) unsigned int*)l,
        16, 0, 0);
}

// ---------------- zero out ----------------
__global__ void zero_kernel(float* __restrict__ out, int n4) {
    int i = blockIdx.x * blockDim.x + threadIdx.x;
    if (i < n4) reinterpret_cast<float4*>(out)[i] = make_float4(0.f, 0.f, 0.f, 0.f);
}

// ---------------- gating: fp32 scores, top-2, softmax (NO atomics) ----------------
__global__ void gating_kernel(const float* __restrict__ x, const float* __restrict__ Wg,
                              int* __restrict__ tok_idx, float* __restrict__ tok_prob) {
    int lane = threadIdx.x & 63;
    int w = threadIdx.x >> 6;
    int t = blockIdx.x * 4 + w;

    float xr[16];
    const float* xp = x + (size_t)t * Dd;
#pragma unroll
    for (int i = 0; i < 16; i++) xr[i] = xp[lane + i * 64];

    float sc[Ee];
    for (int e = 0; e < Ee; e++) {
        const float* wp = Wg + (size_t)e * Dd;
        float p = 0.f;
#pragma unroll
        for (int i = 0; i < 16; i++) p += xr[i] * wp[lane + i * 64];
        for (int off = 32; off > 0; off >>= 1) p += __shfl_xor(p, off);
        sc[e] = p;
    }
    if (lane == 0) {
        int e1 = 0, e2 = 0;
        float b1 = -1e30f, b2 = -1e30f;
        for (int e = 0; e < Ee; e++) {
            float s = sc[e];
            if (s > b1) { b2 = b1; e2 = e1; b1 = s; e1 = e; }
            else if (s > b2) { b2 = s; e2 = e; }
        }
        float p1 = 1.f / (1.f + expf(b2 - b1));
        float p2 = 1.f - p1;
        tok_idx[t * 2 + 0] = e1;
        tok_idx[t * 2 + 1] = e2;
        tok_prob[t * 2 + 0] = p1;
        tok_prob[t * 2 + 1] = p2;
    }
}

// ---------------- route: fused count + scan + stable scatter, one block ----------------
// 1024 threads x 8 items = 8192 (t,k) assignments. No global atomics, deterministic.
__global__ __launch_bounds__(1024) void route_kernel(
    const int* __restrict__ tok_idx, const float* __restrict__ tok_prob,
    int* __restrict__ meta, int* __restrict__ list_tok,
    float* __restrict__ list_prob) {
    int tid = threadIdx.x;
    int lane = tid & 63, w = tid >> 6;   // 16 waves

    int e_loc[8];
#pragma unroll
    for (int j = 0; j < 8; j++) e_loc[j] = tok_idx[tid * 8 + j];

    // private histogram (static indexing only)
    int h[Ee];
#pragma unroll
    for (int e = 0; e < Ee; e++) {
        int c = 0;
#pragma unroll
        for (int j = 0; j < 8; j++) c += (e_loc[j] == e) ? 1 : 0;
        h[e] = c;
    }

    // per-expert exclusive prefix across the wave's 64 lanes + wave totals
    int pre[Ee], tot[Ee];
#pragma unroll
    for (int e = 0; e < Ee; e++) {
        int v = h[e];
        for (int d = 1; d < 64; d <<= 1) {
            int u = __shfl_up(v, d, 64);
            if (lane >= d) v += u;
        }
        pre[e] = v - h[e];
        tot[e] = __shfl(v, 63, 64);
    }

    __shared__ int wtot[16][Ee];
    __shared__ int wbase[16][Ee];
    __shared__ int ebase[Ee];
    if (lane == 0)
#pragma unroll
        for (int e = 0; e < Ee; e++) wtot[w][e] = tot[e];
    __syncthreads();
    if (tid == 0) {
        int etot[Ee];
        for (int e = 0; e < Ee; e++) {
            int s = 0;
            for (int ww = 0; ww < 16; ww++) { wbase[ww][e] = s; s += wtot[ww][e]; }
            etot[e] = s;
        }
        int b = 0;
        for (int e = 0; e < Ee; e++) {
            ebase[e] = b;
            meta[e] = etot[e];       // counts
            meta[16 + e] = b;        // bases
            b += etot[e];
        }
    }
    __syncthreads();

    int off[Ee];
#pragma unroll
    for (int e = 0; e < Ee; e++) off[e] = ebase[e] + wbase[w][e] + pre[e];

#pragma unroll
    for (int j = 0; j < 8; j++) {
        int item = tid * 8 + j;
        int el = e_loc[j];
        int pos = 0;
#pragma unroll
        for (int e = 0; e < Ee; e++) {
            if (el == e) { pos = off[e]; off[e] = pos + 1; }
        }
        list_tok[pos] = item >> 1;
        list_prob[pos] = tok_prob[item];
    }
}

// ---------------- fp32 -> bf16 convert ----------------
__global__ void cvt_kernel(const float* __restrict__ src, unsigned short* __restrict__ dst, int n4) {
    int i = blockIdx.x * blockDim.x + threadIdx.x;
    if (i >= n4) return;
    float4 v = reinterpret_cast<const float4*>(src)[i];
    uint2 o;
    o.x = (unsigned)f2bf(v.x) | ((unsigned)f2bf(v.y) << 16);
    o.y = (unsigned)f2bf(v.z) | ((unsigned)f2bf(v.w) << 16);
    reinterpret_cast<uint2*>(dst)[i] = o;
}

// ---------------- manual fp32->bf16 LDS staging (fallback path only, linear) ----------------
__device__ __forceinline__ void stage16(unsigned short* dst, const float* src) {
    const float4* s = reinterpret_cast<const float4*>(src);
    float4 v0 = s[0], v1 = s[1], v2 = s[2], v3 = s[3];
    uint4 o0, o1;
    o0.x = (unsigned)f2bf(v0.x) | ((unsigned)f2bf(v0.y) << 16);
    o0.y = (unsigned)f2bf(v0.z) | ((unsigned)f2bf(v0.w) << 16);
    o0.z = (unsigned)f2bf(v1.x) | ((unsigned)f2bf(v1.y) << 16);
    o0.w = (unsigned)f2bf(v1.z) | ((unsigned)f2bf(v1.w) << 16);
    o1.x = (unsigned)f2bf(v2.x) | ((unsigned)f2bf(v2.y) << 16);
    o1.y = (unsigned)f2bf(v2.z) | ((unsigned)f2bf(v2.w) << 16);
    o1.z = (unsigned)f2bf(v3.x) | ((unsigned)f2bf(v3.y) << 16);
    o1.w = (unsigned)f2bf(v3.z) | ((unsigned)f2bf(v3.w) << 16);
    uint4* d = reinterpret_cast<uint4*>(dst);
    d[0] = o0;
    d[1] = o1;
}

// ============ fused gemm1: hidden = silu(x W1^T) * (x W2^T), routed rows ============
// 128x128 tile, BK=32, dual accumulator. Counted-vmcnt 2-deep pipeline:
// raw s_barrier + s_waitcnt vmcnt(6) -- next tile's 6 loads stay in flight.
// LDS chunk swizzle: LDS[row][c] holds global chunk c ^ ((row>>1)&3); reads XOR back.
__global__ __launch_bounds__(256, 2) void rgemm12_kernel(
    const unsigned short* __restrict__ A,      // xb
    const unsigned short* __restrict__ B1w,    // W1b
    const unsigned short* __restrict__ B2w,    // W2b
    unsigned short* __restrict__ hout,         // hidden (bf16)
    const int* __restrict__ list_tok, const int* __restrict__ meta) {
    int e = blockIdx.z;
    int cnt = meta[e];
    int m0 = blockIdx.y * 128;
    if (m0 >= cnt) return;
    int bs = meta[16 + e];
    int n0 = blockIdx.x * 128;

    __shared__ unsigned short sA[2 * 128 * 32];
    __shared__ unsigned short sB1[2 * 128 * 32];
    __shared__ unsigned short sB2[2 * 128 * 32];

    int tid = threadIdx.x;
    int lane = tid & 63, w = tid >> 6;
    int wm = w >> 1, wn = w & 1;
    int lane15 = lane & 15, quad = lane >> 4;

    // staging geometry: wave w stages rows [w*32, w*32+16) then +16.
    // swizzled source chunk: lane's row jr has (jr>>1)&3 == (lane>>3)&3.
    int jr = w * 32 + (lane >> 2);
    int c8 = (((lane & 3) ^ ((lane >> 3) & 3)) * 8);
    unsigned short* ldsA0  = sA  + w * 1024;
    unsigned short* ldsA1  = ldsA0 + 512;
    unsigned short* ldsB10 = sB1 + w * 1024;
    unsigned short* ldsB11 = ldsB10 + 512;
    unsigned short* ldsB20 = sB2 + w * 1024;
    unsigned short* ldsB21 = ldsB20 + 512;

    int r0 = m0 + jr;      if (r0 >= cnt) r0 = cnt - 1;
    int r1 = m0 + jr + 16; if (r1 >= cnt) r1 = cnt - 1;
    size_t ar0 = (size_t)list_tok[bs + r0];
    size_t ar1 = (size_t)list_tok[bs + r1];
    const unsigned short* a0 = A + ar0 * Dd + c8;
    const unsigned short* a1 = A + ar1 * Dd + c8;
    const unsigned short* b10 = B1w + ((size_t)e * Ff + n0 + jr) * Dd + c8;
    const unsigned short* b11 = b10 + (size_t)16 * Dd;
    const unsigned short* b20 = B2w + ((size_t)e * Ff + n0 + jr) * Dd + c8;
    const unsigned short* b21 = b20 + (size_t)16 * Dd;

    // read-side swizzle: fragment row is (..+lane15); (row>>1)&3 == (lane15>>1)&3,
    // independent of mi/wm -> folds into the base pointer.
    int rsw = (lane15 >> 1) & 3;
    const unsigned short* sAr  = &sA [(wm * 64 + lane15) * 32 + (quad ^ rsw) * 8];
    const unsigned short* sB1r = &sB1[(wn * 64 + lane15) * 32 + (quad ^ rsw) * 8];
    const unsigned short* sB2r = &sB2[(wn * 64 + lane15) * 32 + (quad ^ rsw) * 8];

    floatx4 acc1[4][4] = {};
    floatx4 acc2[4][4] = {};

    // prologue: stage tiles 0 and 1 (12 loads in flight)
#pragma unroll
    for (int t = 0; t < 2; t++) {
        int k = t * 32, o = t * 4096;
        gload16(a0 + k,  ldsA0  + o);
        gload16(a1 + k,  ldsA1  + o);
        gload16(b10 + k, ldsB10 + o);
        gload16(b11 + k, ldsB11 + o);
        gload16(b20 + k, ldsB20 + o);
        gload16(b21 + k, ldsB21 + o);
    }

    int cur = 0;
    for (int t = 0; t < 32; ++t) {
        // wait ONLY this tile's 6 loads (next tile's 6 stay in flight)
        if (t < 31) asm volatile("s_waitcnt vmcnt(6)" ::: "memory");
        else        asm volatile("s_waitcnt vmcnt(0)" ::: "memory");
        __builtin_amdgcn_s_barrier();
        asm volatile("" ::: "memory");

        int o = cur * 4096;
        short8 af[4], b1f[4], b2f[4];
#pragma unroll
        for (int i = 0; i < 4; i++) {
            af[i]  = *reinterpret_cast<const short8*>(sAr  + o + i * 16 * 32);
            b1f[i] = *reinterpret_cast<const short8*>(sB1r + o + i * 16 * 32);
            b2f[i] = *reinterpret_cast<const short8*>(sB2r + o + i * 16 * 32);
        }
        __builtin_amdgcn_s_setprio(1);
#pragma unroll
        for (int mi = 0; mi < 4; mi++)
#pragma unroll
            for (int ni = 0; ni < 4; ni++) {
                acc1[mi][ni] = __builtin_amdgcn_mfma_f32_16x16x32_bf16(af[mi], b1f[ni], acc1[mi][ni], 0, 0, 0);
                acc2[mi][ni] = __builtin_amdgcn_mfma_f32_16x16x32_bf16(af[mi], b2f[ni], acc2[mi][ni], 0, 0, 0);
            }
        __builtin_amdgcn_s_setprio(0);
        asm volatile("" ::: "memory");
        __builtin_amdgcn_s_barrier();   // all waves done reading buf[cur]
        asm volatile("" ::: "memory");
        if (t + 2 < 32) {               // restage buf[cur] with tile t+2
            int k = (t + 2) * 32;
            gload16(a0 + k,  ldsA0  + o);
            gload16(a1 + k,  ldsA1  + o);
            gload16(b10 + k, ldsB10 + o);
            gload16(b11 + k, ldsB11 + o);
            gload16(b20 + k, ldsB20 + o);
            gload16(b21 + k, ldsB21 + o);
        }
        cur ^= 1;
    }

    // epilogue: hidden = silu(h1) * h2, silu on full-precision acc
#pragma unroll
    for (int mi = 0; mi < 4; mi++) {
#pragma unroll
        for (int i = 0; i < 4; i++) {
            int rr = m0 + wm * 64 + mi * 16 + quad * 4 + i;
            if (rr < cnt) {
                int pos = bs + rr;
                unsigned short* hp = hout + (size_t)pos * Ff + n0 + wn * 64;
#pragma unroll
                for (int ni = 0; ni < 4; ni++) {
                    float h1 = acc1[mi][ni][i];
                    float h2 = acc2[mi][ni][i];
                    float hv = h1 / (1.f + expf(-h1)) * h2;
                    hp[ni * 16 + lane15] = f2bf(hv);
                }
            }
        }
    }
}

// ============ routed single-acc GEMM ============
// EPI 2 = fused combine: atomicAdd(out[tok], prob * C)  (out pre-zeroed)
// bf16 path: counted-vmcnt 2-deep pipeline (vmcnt(4)); fp32 fallback: __syncthreads.
template <typename WT, int EPI>
__global__ __launch_bounds__(256) void rgemm_kernel(
    const unsigned short* __restrict__ A,      // row source (xb or hidden), stride AK
    const WT* __restrict__ Bw,                 // weights, rows of length AK
    unsigned short* __restrict__ h1raw,        // EPI 0 write / EPI 1 read
    unsigned short* __restrict__ hout,         // EPI 1 write
    float* __restrict__ out,                   // EPI 2: token-indexed atomic output
    const int* __restrict__ list_tok, const float* __restrict__ list_prob,
    const int* __restrict__ meta,
    int AK, int BN, int arow_is_list) {
    constexpr bool BF = (sizeof(WT) == 2);
    int e = blockIdx.z;
    int cnt = meta[e];
    int m0 = blockIdx.y * 128;
    if (m0 >= cnt) return;
    int bs = meta[16 + e];
    int n0 = blockIdx.x * 128;

    __shared__ unsigned short sA[2 * 128 * 32];
    __shared__ unsigned short sB[2 * 128 * 32];

    int tid = threadIdx.x;
    int lane = tid & 63, w = tid >> 6;
    int wm = w >> 1, wn = w & 1;
    int lane15 = lane & 15, quad = lane >> 4;

    // async staging geometry: wave w stages rows [w*32, w*32+16) then +16
    int jr = w * 32 + (lane >> 2);
    int c8 = BF ? ((((lane & 3) ^ ((lane >> 3) & 3))) * 8) : ((lane & 3) * 8);
    unsigned short* ldsA0 = sA + w * 1024;
    unsigned short* ldsA1 = ldsA0 + 512;
    unsigned short* ldsB0 = sB + w * 1024;
    unsigned short* ldsB1 = ldsB0 + 512;

    int r0 = m0 + jr;      if (r0 >= cnt) r0 = cnt - 1;
    int r1 = m0 + jr + 16; if (r1 >= cnt) r1 = cnt - 1;
    size_t ar0 = arow_is_list ? (size_t)list_tok[bs + r0] : (size_t)(bs + r0);
    size_t ar1 = arow_is_list ? (size_t)list_tok[bs + r1] : (size_t)(bs + r1);
    const unsigned short* a0 = A + ar0 * AK + c8;
    const unsigned short* a1 = A + ar1 * AK + c8;

    const WT *b0 = nullptr, *b1 = nullptr, *bmp = nullptr;
    unsigned short* sBw = nullptr;
    if constexpr (BF) {
        b0 = Bw + ((size_t)e * BN + n0 + jr) * AK + c8;
        b1 = Bw + ((size_t)e * BN + n0 + jr + 16) * AK + c8;
    } else {
        int row = tid >> 1, colb = (tid & 1) * 16;
        bmp = Bw + ((size_t)e * BN + n0 + row) * AK + colb;
        sBw = &sB[row * 32 + colb];
    }

    int rsw = BF ? ((lane15 >> 1) & 3) : 0;
    const unsigned short* sAr = &sA[(wm * 64 + lane15) * 32 + (quad ^ rsw) * 8];
    const unsigned short* sBr = &sB[(wn * 64 + lane15) * 32 + (quad ^ rsw) * 8];

    floatx4 acc[4][4] = {};

    if constexpr (BF) {
        int NT = AK >> 5;
        // prologue: stage tiles 0 and 1 (8 loads in flight)
#pragma unroll
        for (int t = 0; t < 2; t++) {
            int k = t * 32, o = t * 4096;
            gload16(a0 + k, ldsA0 + o);
            gload16(a1 + k, ldsA1 + o);
            gload16(b0 + k, ldsB0 + o);
            gload16(b1 + k, ldsB1 + o);
        }
        int cur = 0;
        for (int t = 0; t < NT; ++t) {
            if (t + 1 < NT) asm volatile("s_waitcnt vmcnt(4)" ::: "memory");
            else            asm volatile("s_waitcnt vmcnt(0)" ::: "memory");
            __builtin_amdgcn_s_barrier();
            asm volatile("" ::: "memory");

            int o = cur * 4096;
            short8 af[4], bfr[4];
#pragma unroll
            for (int i = 0; i < 4; i++) {
                af[i]  = *reinterpret_cast<const short8*>(sAr + o + i * 16 * 32);
                bfr[i] = *reinterpret_cast<const short8*>(sBr + o + i * 16 * 32);
            }
            __builtin_amdgcn_s_setprio(1);
#pragma unroll
            for (int mi = 0; mi < 4; mi++)
#pragma unroll
                for (int ni = 0; ni < 4; ni++)
                    acc[mi][ni] = __builtin_amdgcn_mfma_f32_16x16x32_bf16(af[mi], bfr[ni], acc[mi][ni], 0, 0, 0);
            __builtin_amdgcn_s_setprio(0);
            asm volatile("" ::: "memory");
            __builtin_amdgcn_s_barrier();
            asm volatile("" ::: "memory");
            if (t + 2 < NT) {
                int k = (t + 2) * 32;
                gload16(a0 + k, ldsA0 + o);
                gload16(a1 + k, ldsA1 + o);
                gload16(b0 + k, ldsB0 + o);
                gload16(b1 + k, ldsB1 + o);
            }
            cur ^= 1;
        }
    } else {
        // fp32 fallback: simple dbuf with __syncthreads (correctness-first path)
        gload16(a0, ldsA0);
        gload16(a1, ldsA1);
        stage16(sBw, bmp);
        __syncthreads();
        int cur = 0;
        for (int k0 = 0; k0 < AK; k0 += 32) {
            if (k0 + 32 < AK) {
                int o = (cur ^ 1) * 4096;
                int k = k0 + 32;
                gload16(a0 + k, ldsA0 + o);
                gload16(a1 + k, ldsA1 + o);
                stage16(sBw + o, bmp + k);
            }
            int o = cur * 4096;
            short8 af[4], bfr[4];
#pragma unroll
            for (int i = 0; i < 4; i++) {
                af[i]  = *reinterpret_cast<const short8*>(sAr + o + i * 16 * 32);
                bfr[i] = *reinterpret_cast<const short8*>(sBr + o + i * 16 * 32);
            }
#pragma unroll
            for (int mi = 0; mi < 4; mi++)
#pragma unroll
                for (int ni = 0; ni < 4; ni++)
                    acc[mi][ni] = __builtin_amdgcn_mfma_f32_16x16x32_bf16(af[mi], bfr[ni], acc[mi][ni], 0, 0, 0);
            __syncthreads();
            cur ^= 1;
        }
    }

#pragma unroll
    for (int mi = 0; mi < 4; mi++) {
#pragma unroll
        for (int i = 0; i < 4; i++) {
            int rr = m0 + wm * 64 + mi * 16 + quad * 4 + i;
            if (rr < cnt) {
                int pos = bs + rr;
                if constexpr (EPI == 0) {
                    unsigned short* hp = h1raw + (size_t)pos * BN + n0 + wn * 64;
#pragma unroll
                    for (int ni = 0; ni < 4; ni++)
                        hp[ni * 16 + lane15] = f2bf(acc[mi][ni][i]);
                } else if constexpr (EPI == 1) {
                    const unsigned short* h1p = h1raw + (size_t)pos * BN + n0 + wn * 64;
                    unsigned short* hp = hout + (size_t)pos * BN + n0 + wn * 64;
#pragma unroll
                    for (int ni = 0; ni < 4; ni++) {
                        float h1 = bf2f(h1p[ni * 16 + lane15]);
                        float h2 = acc[mi][ni][i];
                        float hv = h1 / (1.f + expf(-h1)) * h2;
                        hp[ni * 16 + lane15] = f2bf(hv);
                    }
                } else {
                    int tok = list_tok[pos];
                    float p = list_prob[pos];
                    float* yp = out + (size_t)tok * BN + n0 + wn * 64;
#pragma unroll
                    for (int ni = 0; ni < 4; ni++)
                        atomicAdd(&yp[ni * 16 + lane15], p * acc[mi][ni][i]);
                }
            }
        }
    }
}

// ---------------- host launch ----------------
extern "C" void kernel_launch(void* const* d_in, const int* in_sizes, int n_in,
                              void* d_out, int out_size, void* d_ws, size_t ws_size,
                              hipStream_t stream) {
    const float* x  = (const float*)d_in[0];
    const float* Wg = (const float*)d_in[1];
    const float* W1 = (const float*)d_in[2];
    const float* W2 = (const float*)d_in[3];
    const float* W3 = (const float*)d_in[4];
    float* out = (float*)d_out;

    char* ws = (char*)d_ws;
    size_t off = 0;
    auto alloc = [&](size_t bytes) -> char* {
        size_t o = off;
        off += (bytes + 255) & ~(size_t)255;
        return ws + o;
    };

    int* meta = (int*)alloc(64 * sizeof(int));
    int* tok_idx = (int*)alloc((size_t)TOK * 2 * sizeof(int));
    float* tok_prob = (float*)alloc((size_t)TOK * 2 * sizeof(float));
    int* list_tok = (int*)alloc((size_t)PAIRS * sizeof(int));
    float* list_prob = (float*)alloc((size_t)PAIRS * sizeof(float));
    unsigned short* xb = (unsigned short*)alloc((size_t)TOK * Dd * sizeof(unsigned short));
    unsigned short* hidden = (unsigned short*)alloc((size_t)PAIRS * Ff * sizeof(unsigned short));
    unsigned short* h1raw = (unsigned short*)alloc((size_t)PAIRS * Ff * sizeof(unsigned short));  // fallback path only

    // bf16 weight copies
    size_t wbytes = (size_t)Ee * Ff * Dd * sizeof(unsigned short);
    bool has_w = (ws_size >= off + 3 * wbytes + 4096);
    unsigned short *W1b = nullptr, *W2b = nullptr, *W3b = nullptr;
    if (has_w) {
        W1b = (unsigned short*)alloc(wbytes);
        W2b = (unsigned short*)alloc(wbytes);
        W3b = (unsigned short*)alloc(wbytes);
    }

    // out pre-zeroed for the atomic-accumulate epilogue
    zero_kernel<<<dim3(TOK * Dd / 4 / 256), dim3(256), 0, stream>>>(out, TOK * Dd / 4);

    gating_kernel<<<dim3(TOK / 4), dim3(256), 0, stream>>>(x, Wg, tok_idx, tok_prob);
    route_kernel<<<dim3(1), dim3(1024), 0, stream>>>(tok_idx, tok_prob, meta,
                                                     list_tok, list_prob);

    int xn4 = TOK * Dd / 4;
    cvt_kernel<<<dim3((xn4 + 255) / 256), dim3(256), 0, stream>>>(x, xb, xn4);

    dim3 g1(Ff / 128, 32, Ee), g2(Dd / 128, 32, Ee), blk(256);

    if (has_w) {
        int wn4 = Ee * Ff * Dd / 4;
        cvt_kernel<<<dim3((wn4 + 255) / 256), blk, 0, stream>>>(W1, W1b, wn4);
        cvt_kernel<<<dim3((wn4 + 255) / 256), blk, 0, stream>>>(W2, W2b, wn4);
        cvt_kernel<<<dim3((wn4 + 255) / 256), blk, 0, stream>>>(W3, W3b, wn4);
        // fused gemm1: hidden = silu(x W1^T) * (x W2^T)
        rgemm12_kernel<<<g1, blk, 0, stream>>>(xb, W1b, W2b, hidden, list_tok, meta);
        // gemm2 + combine: out[tok] += prob * (hidden W3^T)
        rgemm_kernel<unsigned short, 2><<<g2, blk, 0, stream>>>(
            hidden, W3b, nullptr, nullptr, out, list_tok, list_prob, meta, Ff, Dd, 0);
    } else {
        rgemm_kernel<float, 0><<<g1, blk, 0, stream>>>(
            xb, W1, h1raw, nullptr, nullptr, list_tok, list_prob, meta, Dd, Ff, 1);
        rgemm_kernel<float, 1><<<g1, blk, 0, stream>>>(
            xb, W2, h1raw, hidden, nullptr, list_tok, list_prob, meta, Dd, Ff, 1);
        rgemm_kernel<float, 2><<<g2, blk, 0, stream>>>(
            hidden, W3, nullptr, nullptr, out, list_tok, list_prob, meta, Ff, Dd, 0);
    }
}